// Round 14
// baseline (133.036 us; speedup 1.0000x reference)
//
#include <hip/hip_runtime.h>
#include <hip/hip_fp16.h>

#define LL 16384
#define HH 128
#define WW 128
#define CC 64
#define NH 8
#define EPSF 1e-7f
#define KVCHUNKS 32

typedef __attribute__((ext_vector_type(8))) _Float16 f16x8;
typedef __attribute__((ext_vector_type(4))) float f32x4;
typedef __attribute__((ext_vector_type(8))) unsigned short u16x8;

// ---------------- Kernel A: qkv 1x1 conv + bias (+relu on q,k) via MFMA hi/lo ----------
__global__ void qkv_kernel(const float* __restrict__ x, const float* __restrict__ w,
                           const float* __restrict__ bias,
                           float* __restrict__ q, float* __restrict__ k, float* __restrict__ v) {
    const int pix0 = blockIdx.x * 128;
    const int b    = blockIdx.y;
    const int sec  = blockIdx.z;
    const int tid  = threadIdx.x;
    const int lane = tid & 63;
    const int wv   = tid >> 6;

    __shared__ _Float16 xh[128][72], xl[128][72];
    __shared__ _Float16 wh[64][72],  wl[64][72];

    {
        const float* xb = x + (size_t)b * CC * LL + pix0;
        for (int idx = tid; idx < 64 * 128; idx += 256) {
            const int ci = idx >> 7;
            const int px = idx & 127;
            const float vv = xb[(size_t)ci * LL + px];
            const _Float16 h = (_Float16)vv;
            xh[px][ci] = h;
            xl[px][ci] = (_Float16)(vv - (float)h);
        }
    }
    {
        const float* wsec = w + (size_t)sec * 64 * 64;
        for (int idx = tid; idx < 64 * 64; idx += 256) {
            const int co = idx >> 6;
            const int ci = idx & 63;
            const float vv = wsec[co * 64 + ci];
            const _Float16 h = (_Float16)vv;
            wh[co][ci] = h;
            wl[co][ci] = (_Float16)(vv - (float)h);
        }
    }
    __syncthreads();

    f32x4 acc[4][2];
#pragma unroll
    for (int ct = 0; ct < 4; ++ct)
#pragma unroll
        for (int pt = 0; pt < 2; ++pt) acc[ct][pt] = (f32x4)0.f;

    const int g8 = (lane >> 4) * 8;
    const int rl = lane & 15;

#pragma unroll
    for (int ks = 0; ks < 2; ++ks) {
        const int kb = ks * 32 + g8;
        f16x8 ah[4], al[4], bh[2], bl[2];
#pragma unroll
        for (int ct = 0; ct < 4; ++ct) {
            ah[ct] = *(const f16x8*)&wh[ct * 16 + rl][kb];
            al[ct] = *(const f16x8*)&wl[ct * 16 + rl][kb];
        }
#pragma unroll
        for (int pt = 0; pt < 2; ++pt) {
            bh[pt] = *(const f16x8*)&xh[wv * 32 + pt * 16 + rl][kb];
            bl[pt] = *(const f16x8*)&xl[wv * 32 + pt * 16 + rl][kb];
        }
#pragma unroll
        for (int ct = 0; ct < 4; ++ct)
#pragma unroll
            for (int pt = 0; pt < 2; ++pt) {
                acc[ct][pt] = __builtin_amdgcn_mfma_f32_16x16x32_f16(ah[ct], bh[pt], acc[ct][pt], 0, 0, 0);
                acc[ct][pt] = __builtin_amdgcn_mfma_f32_16x16x32_f16(ah[ct], bl[pt], acc[ct][pt], 0, 0, 0);
                acc[ct][pt] = __builtin_amdgcn_mfma_f32_16x16x32_f16(al[ct], bh[pt], acc[ct][pt], 0, 0, 0);
            }
    }

    float* dst = (sec == 0) ? q : (sec == 1) ? k : v;
    const bool do_relu = (sec < 2);
#pragma unroll
    for (int ct = 0; ct < 4; ++ct) {
        const int co_b = ct * 16 + (lane >> 4) * 4;
#pragma unroll
        for (int pt = 0; pt < 2; ++pt) {
            const int px = pix0 + wv * 32 + pt * 16 + rl;
#pragma unroll
            for (int j = 0; j < 4; ++j) {
                const int co = co_b + j;
                float val = acc[ct][pt][j] + bias[sec * 64 + co];
                if (do_relu) val = fmaxf(val, 0.f);
                dst[((size_t)b * 64 + co) * LL + px] = val;
            }
        }
    }
}

// ---------------- Kernel B: KV/KS partials, K staged in LDS ----------------
__global__ void kv_kernel(const float* __restrict__ k, const float* __restrict__ v,
                          float* __restrict__ KVp) {
    const int chunk = blockIdx.x;
    const int h = blockIdx.y;
    const int b = blockIdx.z;
    const int tid = threadIdx.x;
    const int c  = tid >> 5;
    const int s  = tid & 31;
    const int half = s >> 4;
    const int sl   = s & 15;
    const int cpb  = half * 4;

    __shared__ float klds[8][6][130];

    {
        const float* kb = k + ((size_t)(b * 64) + 8 * h) * LL;
        for (int t = tid; t < 8 * 6 * 130; t += 256) {
            const int ch = t / 780;
            const int r1 = t - ch * 780;
            const int lr = r1 / 130;
            const int cx = r1 - lr * 130;
            const int gy = chunk * 4 + lr - 1;
            const int gx = cx - 1;
            const bool ok = (gy >= 0 && gy < HH && gx >= 0 && gx < WW);
            klds[ch][lr][cx] = ok ? kb[(size_t)ch * LL + gy * WW + gx] : 0.f;
        }
    }
    __syncthreads();

    const float* vb = v + ((size_t)(b * 64) + 8 * h + cpb) * LL;

    float kv4[9][4] = {{0.f}};
    float ks[9] = {0.f};

    for (int r = 0; r < 4; ++r) {
        const int y = chunk * 4 + r;
        for (int g = 0; g < 8; ++g) {
            const int col = g * 16 + sl;
            float vv[4];
#pragma unroll
            for (int cp = 0; cp < 4; ++cp) vv[cp] = vb[(size_t)cp * LL + y * WW + col];
            float k9[9];
#pragma unroll
            for (int dy = 0; dy < 3; ++dy)
#pragma unroll
                for (int dx = 0; dx < 3; ++dx)
                    k9[dy * 3 + dx] = klds[c][r + dy][col + dx];
#pragma unroll
            for (int p = 0; p < 9; ++p) {
                ks[p] += k9[p];
#pragma unroll
                for (int cp = 0; cp < 4; ++cp)
                    kv4[p][cp] = fmaf(k9[p], vv[cp], kv4[p][cp]);
            }
        }
    }

#pragma unroll
    for (int p = 0; p < 9; ++p) {
#pragma unroll
        for (int m = 8; m >= 1; m >>= 1) ks[p] += __shfl_xor(ks[p], m);
#pragma unroll
        for (int cp = 0; cp < 4; ++cp) {
#pragma unroll
            for (int m = 8; m >= 1; m >>= 1) kv4[p][cp] += __shfl_xor(kv4[p][cp], m);
        }
    }

    if (sl == 0) {
        float* dst = KVp + (((size_t)(b * NH + h) * KVCHUNKS) + chunk) * 648;
#pragma unroll
        for (int p = 0; p < 9; ++p) {
#pragma unroll
            for (int cp = 0; cp < 4; ++cp)
                dst[(c * 9 + p) * 8 + cpb + cp] = kv4[p][cp];
            if (half == 0) dst[576 + c * 9 + p] = ks[p];
        }
    }
}

// ---------------- Kernel B2: reduce 32 chunk-partials -> KV, KS ----------------
__global__ void kv_finalize(const float* __restrict__ KVp,
                            float* __restrict__ KV, float* __restrict__ KS) {
    const int bh = blockIdx.x;
    const float* src = KVp + (size_t)bh * KVCHUNKS * 648;
    for (int idx = threadIdx.x; idx < 648; idx += 256) {
        float s0 = 0.f, s1 = 0.f, s2 = 0.f, s3 = 0.f;
#pragma unroll
        for (int ch = 0; ch < KVCHUNKS; ch += 4) {
            s0 += src[(ch + 0) * 648 + idx];
            s1 += src[(ch + 1) * 648 + idx];
            s2 += src[(ch + 2) * 648 + idx];
            s3 += src[(ch + 3) * 648 + idx];
        }
        const float sum = (s0 + s1) + (s2 + s3);
        if (idx < 576) KV[(size_t)bh * 576 + idx] = sum;
        else           KS[(size_t)bh * 72 + (idx - 576)] = sum;
    }
}

// ---------------- Kernel C: attn (R10 global-load version), writes packed f16 hi/lo --
__global__ void attn_kernel(const float* __restrict__ q, const float* __restrict__ KV,
                            const float* __restrict__ KS, unsigned int* __restrict__ aohl) {
    const int y = blockIdx.x;
    const int h = blockIdx.y;
    const int b = blockIdx.z;
    const int col = threadIdx.x;

    float out[8] = {0.f};
    float den = 0.f;
    const int kvbase = (b * NH + h) * 8;

    for (int c = 0; c < 8; ++c) {
        const float* qc = q + ((size_t)(b * 64) + 8 * h + c) * LL;
        float q9[9];
#pragma unroll
        for (int dy = -1; dy <= 1; ++dy)
#pragma unroll
            for (int dx = -1; dx <= 1; ++dx) {
                const int yy = y + dy, xx = col + dx;
                const bool ok = (yy >= 0 && yy < HH && xx >= 0 && xx < WW);
                q9[(dy + 1) * 3 + (dx + 1)] = ok ? qc[yy * WW + xx] : 0.f;
            }
        const float* kvr = KV + ((size_t)(kvbase + c) * 9) * 8;
        const float* ksr = KS + (size_t)(kvbase + c) * 9;
#pragma unroll
        for (int p = 0; p < 9; ++p) {
            const float qv = q9[p];
            den += qv * ksr[p];
#pragma unroll
            for (int cp = 0; cp < 8; ++cp) out[cp] += qv * kvr[p * 8 + cp];
        }
    }
    const float inv = 1.f / (den + EPSF);
    const int pix = y * WW + col;
#pragma unroll
    for (int cp = 0; cp < 8; ++cp) {
        const float val = out[cp] * inv;
        const _Float16 hf = (_Float16)val;
        const _Float16 lf = (_Float16)(val - (float)hf);
        unsigned short hb, lb;
        __builtin_memcpy(&hb, &hf, 2);
        __builtin_memcpy(&lb, &lf, 2);
        aohl[((size_t)(b * 64) + h * 8 + cp) * LL + pix] = (unsigned int)hb | ((unsigned int)lb << 16);
    }
}

// ---------------- Kernel W: pre-split proj_w into MFMA fragment layout ----------------
__global__ void wprep_kernel(const float* __restrict__ w, unsigned short* __restrict__ wfrag) {
    const int idx = blockIdx.x * 256 + threadIdx.x;   // 16*64*64 = 65536
    const int k  = idx & 63;
    const int co = (idx >> 6) & 63;
    const int ks = idx >> 12;
    const int kg = ks * 64 + k;
    const int ci = kg >> 4, tap = kg & 15;
    const float vv = (tap < 9) ? w[(co * 64 + ci) * 9 + tap] : 0.f;
    const _Float16 h = (_Float16)vv;
    const _Float16 l = (_Float16)(vv - (float)h);
    unsigned short hb, lb;
    __builtin_memcpy(&hb, &h, 2);
    __builtin_memcpy(&lb, &l, 2);
    const int kx = (((k >> 3) ^ (co & 7)) << 3) | (k & 7);
    wfrag[(((size_t)ks * 2 + 0) * 64 + co) * 64 + kx] = hb;
    wfrag[(((size_t)ks * 2 + 1) * 64 + co) * 64 + kx] = lb;
}

// ---------------- Kernel D: 3x3 conv via MFMA; P dbuf in LDS, W direct from L1/L2 ----
// grid 1024 (XCD-chunk swizzled): block -> (b, row y, col-half), 64 pix.
// 16 ksteps of K=64 (4 ci). One barrier/kstep; P prefetched into named regs after the
// barrier. W A-fragments loaded per-lane straight from wfrag (same 16 KB for every
// block -> L1-resident) — no wlds: LDS = 32 KB -> 4 blocks/CU.
#define CONV_PREFETCH(KS)                                                        \
    do {                                                                         \
        const unsigned int* src_ = aob + (size_t)((KS) * 4 + scis) * LL;         \
        pf0 = (oky0 && okxm) ? src_[offm - WW] : 0u;                             \
        pf1 = oky0 ? src_[off0 - WW] : 0u;                                       \
        pf2 = (oky0 && okxp) ? src_[offp - WW] : 0u;                             \
        pf3 = okxm ? src_[offm] : 0u;                                            \
        pf4 = src_[off0];                                                        \
        pf5 = okxp ? src_[offp] : 0u;                                            \
        pf6 = (oky2 && okxm) ? src_[offm + WW] : 0u;                             \
        pf7 = oky2 ? src_[off0 + WW] : 0u;                                       \
        pf8 = (oky2 && okxp) ? src_[offp + WW] : 0u;                             \
    } while (0)

__global__ __launch_bounds__(256) void conv_kernel(const unsigned int* __restrict__ aohl,
                                                   const unsigned short* __restrict__ wfrag,
                                                   const float* __restrict__ bias,
                                                   float* __restrict__ out) {
    const int bid = blockIdx.x;
    const int swz = (bid & 7) * 128 + (bid >> 3);   // XCD-chunked
    const int b = swz >> 8;
    const int rem = swz & 255;
    const int y = rem >> 1;
    const int colbase = (rem & 1) * 64;
    const int tid = threadIdx.x;
    const int lane = tid & 63;
    const int wv = tid >> 6;
    const int rl = lane & 15;
    const int g  = lane >> 4;

    __shared__ unsigned short plds[2][2 * 64 * 64];   // 2 x 16384 B (dbuf)

    f32x4 acc[4];
#pragma unroll
    for (int ct = 0; ct < 4; ++ct) acc[ct] = (f32x4)0.f;

    const unsigned int* aob = aohl + (size_t)b * 64 * LL;
    const int spix = tid & 63;       // staging pixel (local)
    const int scis = tid >> 6;       // staging ci-select 0..3

    // fixed staging geometry
    const int xc   = colbase + spix;
    const int off0 = y * WW + xc;
    const int offm = off0 - 1;
    const int offp = off0 + 1;
    const bool oky0 = (y > 0);
    const bool oky2 = (y < HH - 1);
    const bool okxm = (xc > 0);
    const bool okxp = (xc < WW - 1);
    const int xs0 = (((2 * scis)     ^ (spix & 7)) << 3);
    const int xs1 = (((2 * scis + 1) ^ (spix & 7)) << 3);

    unsigned int pf0, pf1, pf2, pf3, pf4, pf5, pf6, pf7, pf8;

    CONV_PREFETCH(0);

    for (int ks = 0; ks < 16; ++ks) {
        const int cur = ks & 1;
        // ---- unpack named regs -> LDS[cur] ----
        {
            unsigned short h16[16], l16[16];
            h16[0] = (unsigned short)(pf0 & 0xffffu);  l16[0] = (unsigned short)(pf0 >> 16);
            h16[1] = (unsigned short)(pf1 & 0xffffu);  l16[1] = (unsigned short)(pf1 >> 16);
            h16[2] = (unsigned short)(pf2 & 0xffffu);  l16[2] = (unsigned short)(pf2 >> 16);
            h16[3] = (unsigned short)(pf3 & 0xffffu);  l16[3] = (unsigned short)(pf3 >> 16);
            h16[4] = (unsigned short)(pf4 & 0xffffu);  l16[4] = (unsigned short)(pf4 >> 16);
            h16[5] = (unsigned short)(pf5 & 0xffffu);  l16[5] = (unsigned short)(pf5 >> 16);
            h16[6] = (unsigned short)(pf6 & 0xffffu);  l16[6] = (unsigned short)(pf6 >> 16);
            h16[7] = (unsigned short)(pf7 & 0xffffu);  l16[7] = (unsigned short)(pf7 >> 16);
            h16[8] = (unsigned short)(pf8 & 0xffffu);  l16[8] = (unsigned short)(pf8 >> 16);
#pragma unroll
            for (int j = 9; j < 16; ++j) { h16[j] = 0; l16[j] = 0; }
            *(u16x8*)&plds[cur][(0 * 64 + spix) * 64 + xs0] = *(u16x8*)&h16[0];
            *(u16x8*)&plds[cur][(0 * 64 + spix) * 64 + xs1] = *(u16x8*)&h16[8];
            *(u16x8*)&plds[cur][(1 * 64 + spix) * 64 + xs0] = *(u16x8*)&l16[0];
            *(u16x8*)&plds[cur][(1 * 64 + spix) * 64 + xs1] = *(u16x8*)&l16[8];
        }
        __syncthreads();
        if (ks < 15) CONV_PREFETCH(ks + 1);   // flies under the MFMA phase

        // ---- MFMA: 2 ksubs x 4 co-tiles x 3 (hi/lo); W frags straight from L1/L2 ----
        const unsigned short* wks = wfrag + (size_t)ks * 8192;
#pragma unroll
        for (int ksub = 0; ksub < 2; ++ksub) {
            const int xs = (((ksub * 4 + g) ^ (rl & 7)) << 3);
            const int row = wv * 16 + rl;
            const f16x8 bh = *(const f16x8*)&plds[cur][(0 * 64 + row) * 64 + xs];
            const f16x8 bl = *(const f16x8*)&plds[cur][(1 * 64 + row) * 64 + xs];
#pragma unroll
            for (int ct = 0; ct < 4; ++ct) {
                const int rowa = ct * 16 + rl;
                const f16x8 ah = *(const f16x8*)&wks[rowa * 64 + xs];          // hl=0
                const f16x8 al = *(const f16x8*)&wks[(64 + rowa) * 64 + xs];   // hl=1
                acc[ct] = __builtin_amdgcn_mfma_f32_16x16x32_f16(ah, bh, acc[ct], 0, 0, 0);
                acc[ct] = __builtin_amdgcn_mfma_f32_16x16x32_f16(ah, bl, acc[ct], 0, 0, 0);
                acc[ct] = __builtin_amdgcn_mfma_f32_16x16x32_f16(al, bh, acc[ct], 0, 0, 0);
            }
        }
    }

#pragma unroll
    for (int ct = 0; ct < 4; ++ct) {
        const int co_b = ct * 16 + g * 4;
        const int px = colbase + wv * 16 + rl;
#pragma unroll
        for (int j = 0; j < 4; ++j) {
            const int co = co_b + j;
            out[((size_t)b * 64 + co) * LL + y * WW + px] = acc[ct][j] + bias[co];
        }
    }
}

extern "C" void kernel_launch(void* const* d_in, const int* in_sizes, int n_in,
                              void* d_out, int out_size, void* d_ws, size_t ws_size,
                              hipStream_t stream) {
    const float* x      = (const float*)d_in[0];
    const float* qkv_w  = (const float*)d_in[1];
    const float* qkv_b  = (const float*)d_in[2];
    const float* proj_w = (const float*)d_in[3];
    const float* proj_b = (const float*)d_in[4];
    float* out = (float*)d_out;
    float* ws  = (float*)d_ws;

    const size_t n1 = (size_t)4 * 64 * LL;      // one B*C*L plane set
    float* qb   = ws;
    float* kb   = ws + n1;
    float* vb   = ws + 2 * n1;
    unsigned int* aohl = (unsigned int*)(ws + 3 * n1);
    float* KV   = ws + 4 * n1;                  // 4*8*8*9*8 = 18432 floats
    float* KS   = KV + 4 * 8 * 8 * 9 * 8;       // 4*8*8*9  = 2304 floats
    float* KVp  = KS + 4 * 8 * 8 * 9;           // 32*32*648 = 663552 floats
    unsigned short* wfrag = (unsigned short*)(KVp + (size_t)32 * KVCHUNKS * 648);  // 131072 halfs

    wprep_kernel<<<256, 256, 0, stream>>>(proj_w, wfrag);
    qkv_kernel<<<dim3(128, 4, 3), 256, 0, stream>>>(x, qkv_w, qkv_b, qb, kb, vb);
    kv_kernel<<<dim3(KVCHUNKS, NH, 4), 256, 0, stream>>>(kb, vb, KVp);
    kv_finalize<<<32, 256, 0, stream>>>(KVp, KV, KS);
    attn_kernel<<<dim3(128, NH, 4), 128, 0, stream>>>(qb, KV, KS, aohl);
    conv_kernel<<<1024, 256, 0, stream>>>(aohl, wfrag, proj_b, out);
}

// Round 15
// 116.218 us; speedup vs baseline: 1.1447x; 1.1447x over previous
//
#include <hip/hip_runtime.h>
#include <hip/hip_fp16.h>

#define LL 16384
#define HH 128
#define WW 128
#define CC 64
#define NH 8
#define EPSF 1e-7f
#define KVCHUNKS 32

typedef __attribute__((ext_vector_type(8))) _Float16 f16x8;
typedef __attribute__((ext_vector_type(4))) float f32x4;
typedef __attribute__((ext_vector_type(8))) unsigned short u16x8;

// ---------------- Kernel A: qkv 1x1 conv + bias (+relu on q,k) via MFMA hi/lo ----------
__global__ void qkv_kernel(const float* __restrict__ x, const float* __restrict__ w,
                           const float* __restrict__ bias,
                           float* __restrict__ q, float* __restrict__ k, float* __restrict__ v) {
    const int pix0 = blockIdx.x * 128;
    const int b    = blockIdx.y;
    const int sec  = blockIdx.z;
    const int tid  = threadIdx.x;
    const int lane = tid & 63;
    const int wv   = tid >> 6;

    __shared__ _Float16 xh[128][72], xl[128][72];
    __shared__ _Float16 wh[64][72],  wl[64][72];

    {
        const float* xb = x + (size_t)b * CC * LL + pix0;
        for (int idx = tid; idx < 64 * 128; idx += 256) {
            const int ci = idx >> 7;
            const int px = idx & 127;
            const float vv = xb[(size_t)ci * LL + px];
            const _Float16 h = (_Float16)vv;
            xh[px][ci] = h;
            xl[px][ci] = (_Float16)(vv - (float)h);
        }
    }
    {
        const float* wsec = w + (size_t)sec * 64 * 64;
        for (int idx = tid; idx < 64 * 64; idx += 256) {
            const int co = idx >> 6;
            const int ci = idx & 63;
            const float vv = wsec[co * 64 + ci];
            const _Float16 h = (_Float16)vv;
            wh[co][ci] = h;
            wl[co][ci] = (_Float16)(vv - (float)h);
        }
    }
    __syncthreads();

    f32x4 acc[4][2];
#pragma unroll
    for (int ct = 0; ct < 4; ++ct)
#pragma unroll
        for (int pt = 0; pt < 2; ++pt) acc[ct][pt] = (f32x4)0.f;

    const int g8 = (lane >> 4) * 8;
    const int rl = lane & 15;

#pragma unroll
    for (int ks = 0; ks < 2; ++ks) {
        const int kb = ks * 32 + g8;
        f16x8 ah[4], al[4], bh[2], bl[2];
#pragma unroll
        for (int ct = 0; ct < 4; ++ct) {
            ah[ct] = *(const f16x8*)&wh[ct * 16 + rl][kb];
            al[ct] = *(const f16x8*)&wl[ct * 16 + rl][kb];
        }
#pragma unroll
        for (int pt = 0; pt < 2; ++pt) {
            bh[pt] = *(const f16x8*)&xh[wv * 32 + pt * 16 + rl][kb];
            bl[pt] = *(const f16x8*)&xl[wv * 32 + pt * 16 + rl][kb];
        }
#pragma unroll
        for (int ct = 0; ct < 4; ++ct)
#pragma unroll
            for (int pt = 0; pt < 2; ++pt) {
                acc[ct][pt] = __builtin_amdgcn_mfma_f32_16x16x32_f16(ah[ct], bh[pt], acc[ct][pt], 0, 0, 0);
                acc[ct][pt] = __builtin_amdgcn_mfma_f32_16x16x32_f16(ah[ct], bl[pt], acc[ct][pt], 0, 0, 0);
                acc[ct][pt] = __builtin_amdgcn_mfma_f32_16x16x32_f16(al[ct], bh[pt], acc[ct][pt], 0, 0, 0);
            }
    }

    float* dst = (sec == 0) ? q : (sec == 1) ? k : v;
    const bool do_relu = (sec < 2);
#pragma unroll
    for (int ct = 0; ct < 4; ++ct) {
        const int co_b = ct * 16 + (lane >> 4) * 4;
#pragma unroll
        for (int pt = 0; pt < 2; ++pt) {
            const int px = pix0 + wv * 32 + pt * 16 + rl;
#pragma unroll
            for (int j = 0; j < 4; ++j) {
                const int co = co_b + j;
                float val = acc[ct][pt][j] + bias[sec * 64 + co];
                if (do_relu) val = fmaxf(val, 0.f);
                dst[((size_t)b * 64 + co) * LL + px] = val;
            }
        }
    }
}

// ---------------- Kernel B: KV/KS partials, K staged in LDS ----------------
__global__ void kv_kernel(const float* __restrict__ k, const float* __restrict__ v,
                          float* __restrict__ KVp) {
    const int chunk = blockIdx.x;
    const int h = blockIdx.y;
    const int b = blockIdx.z;
    const int tid = threadIdx.x;
    const int c  = tid >> 5;
    const int s  = tid & 31;
    const int half = s >> 4;
    const int sl   = s & 15;
    const int cpb  = half * 4;

    __shared__ float klds[8][6][130];

    {
        const float* kb = k + ((size_t)(b * 64) + 8 * h) * LL;
        for (int t = tid; t < 8 * 6 * 130; t += 256) {
            const int ch = t / 780;
            const int r1 = t - ch * 780;
            const int lr = r1 / 130;
            const int cx = r1 - lr * 130;
            const int gy = chunk * 4 + lr - 1;
            const int gx = cx - 1;
            const bool ok = (gy >= 0 && gy < HH && gx >= 0 && gx < WW);
            klds[ch][lr][cx] = ok ? kb[(size_t)ch * LL + gy * WW + gx] : 0.f;
        }
    }
    __syncthreads();

    const float* vb = v + ((size_t)(b * 64) + 8 * h + cpb) * LL;

    float kv4[9][4] = {{0.f}};
    float ks[9] = {0.f};

    for (int r = 0; r < 4; ++r) {
        const int y = chunk * 4 + r;
        for (int g = 0; g < 8; ++g) {
            const int col = g * 16 + sl;
            float vv[4];
#pragma unroll
            for (int cp = 0; cp < 4; ++cp) vv[cp] = vb[(size_t)cp * LL + y * WW + col];
            float k9[9];
#pragma unroll
            for (int dy = 0; dy < 3; ++dy)
#pragma unroll
                for (int dx = 0; dx < 3; ++dx)
                    k9[dy * 3 + dx] = klds[c][r + dy][col + dx];
#pragma unroll
            for (int p = 0; p < 9; ++p) {
                ks[p] += k9[p];
#pragma unroll
                for (int cp = 0; cp < 4; ++cp)
                    kv4[p][cp] = fmaf(k9[p], vv[cp], kv4[p][cp]);
            }
        }
    }

#pragma unroll
    for (int p = 0; p < 9; ++p) {
#pragma unroll
        for (int m = 8; m >= 1; m >>= 1) ks[p] += __shfl_xor(ks[p], m);
#pragma unroll
        for (int cp = 0; cp < 4; ++cp) {
#pragma unroll
            for (int m = 8; m >= 1; m >>= 1) kv4[p][cp] += __shfl_xor(kv4[p][cp], m);
        }
    }

    if (sl == 0) {
        float* dst = KVp + (((size_t)(b * NH + h) * KVCHUNKS) + chunk) * 648;
#pragma unroll
        for (int p = 0; p < 9; ++p) {
#pragma unroll
            for (int cp = 0; cp < 4; ++cp)
                dst[(c * 9 + p) * 8 + cpb + cp] = kv4[p][cp];
            if (half == 0) dst[576 + c * 9 + p] = ks[p];
        }
    }
}

// ---------------- Kernel B2: reduce 32 chunk-partials -> KV, KS ----------------
__global__ void kv_finalize(const float* __restrict__ KVp,
                            float* __restrict__ KV, float* __restrict__ KS) {
    const int bh = blockIdx.x;
    const float* src = KVp + (size_t)bh * KVCHUNKS * 648;
    for (int idx = threadIdx.x; idx < 648; idx += 256) {
        float s0 = 0.f, s1 = 0.f, s2 = 0.f, s3 = 0.f;
#pragma unroll
        for (int ch = 0; ch < KVCHUNKS; ch += 4) {
            s0 += src[(ch + 0) * 648 + idx];
            s1 += src[(ch + 1) * 648 + idx];
            s2 += src[(ch + 2) * 648 + idx];
            s3 += src[(ch + 3) * 648 + idx];
        }
        const float sum = (s0 + s1) + (s2 + s3);
        if (idx < 576) KV[(size_t)bh * 576 + idx] = sum;
        else           KS[(size_t)bh * 72 + (idx - 576)] = sum;
    }
}

// ---------------- Kernel C: attn (global-load version), writes packed f16 hi/lo ------
__global__ void attn_kernel(const float* __restrict__ q, const float* __restrict__ KV,
                            const float* __restrict__ KS, unsigned int* __restrict__ aohl) {
    const int y = blockIdx.x;
    const int h = blockIdx.y;
    const int b = blockIdx.z;
    const int col = threadIdx.x;

    float out[8] = {0.f};
    float den = 0.f;
    const int kvbase = (b * NH + h) * 8;

    for (int c = 0; c < 8; ++c) {
        const float* qc = q + ((size_t)(b * 64) + 8 * h + c) * LL;
        float q9[9];
#pragma unroll
        for (int dy = -1; dy <= 1; ++dy)
#pragma unroll
            for (int dx = -1; dx <= 1; ++dx) {
                const int yy = y + dy, xx = col + dx;
                const bool ok = (yy >= 0 && yy < HH && xx >= 0 && xx < WW);
                q9[(dy + 1) * 3 + (dx + 1)] = ok ? qc[yy * WW + xx] : 0.f;
            }
        const float* kvr = KV + ((size_t)(kvbase + c) * 9) * 8;
        const float* ksr = KS + (size_t)(kvbase + c) * 9;
#pragma unroll
        for (int p = 0; p < 9; ++p) {
            const float qv = q9[p];
            den += qv * ksr[p];
#pragma unroll
            for (int cp = 0; cp < 8; ++cp) out[cp] += qv * kvr[p * 8 + cp];
        }
    }
    const float inv = 1.f / (den + EPSF);
    const int pix = y * WW + col;
#pragma unroll
    for (int cp = 0; cp < 8; ++cp) {
        const float val = out[cp] * inv;
        const _Float16 hf = (_Float16)val;
        const _Float16 lf = (_Float16)(val - (float)hf);
        unsigned short hb, lb;
        __builtin_memcpy(&hb, &hf, 2);
        __builtin_memcpy(&lb, &lf, 2);
        aohl[((size_t)(b * 64) + h * 8 + cp) * LL + pix] = (unsigned int)hb | ((unsigned int)lb << 16);
    }
}

// ---------------- Kernel W: pre-split proj_w into MFMA fragment layout ----------------
__global__ void wprep_kernel(const float* __restrict__ w, unsigned short* __restrict__ wfrag) {
    const int idx = blockIdx.x * 256 + threadIdx.x;   // 16*64*64 = 65536
    const int k  = idx & 63;
    const int co = (idx >> 6) & 63;
    const int ks = idx >> 12;
    const int kg = ks * 64 + k;
    const int ci = kg >> 4, tap = kg & 15;
    const float vv = (tap < 9) ? w[(co * 64 + ci) * 9 + tap] : 0.f;
    const _Float16 h = (_Float16)vv;
    const _Float16 l = (_Float16)(vv - (float)h);
    unsigned short hb, lb;
    __builtin_memcpy(&hb, &h, 2);
    __builtin_memcpy(&lb, &l, 2);
    const int kx = (((k >> 3) ^ (co & 7)) << 3) | (k & 7);
    wfrag[(((size_t)ks * 2 + 0) * 64 + co) * 64 + kx] = hb;
    wfrag[(((size_t)ks * 2 + 1) * 64 + co) * 64 + kx] = lb;
}

// ---------------- Kernel D: 3x3 conv via MFMA, dbuf LDS + depth-2 reg prefetch ------
// grid 1024 (XCD-chunk swizzled): block -> (b, row y, col-half), 64 pix.
// 16 ksteps of K=64 (4 ci); 2 ksteps per loop body (sets A/B, buffers 0/1).
// Prefetch for kstep+2 issued right after each barrier -> in-flight window spans
// two MFMA phases (~2x R13's). All prefetch regs NAMED scalars (no scratch).
#define CONV_PF(KS, P0,P1,P2,P3,P4,P5,P6,P7,P8, W0,W1,W2,W3)                     \
    do {                                                                         \
        const unsigned int* src_ = aob + (size_t)((KS) * 4 + scis) * LL;         \
        P0 = (oky0 && okxm) ? src_[offm - WW] : 0u;                              \
        P1 = oky0 ? src_[off0 - WW] : 0u;                                        \
        P2 = (oky0 && okxp) ? src_[offp - WW] : 0u;                              \
        P3 = okxm ? src_[offm] : 0u;                                             \
        P4 = src_[off0];                                                         \
        P5 = okxp ? src_[offp] : 0u;                                             \
        P6 = (oky2 && okxm) ? src_[offm + WW] : 0u;                              \
        P7 = oky2 ? src_[off0 + WW] : 0u;                                        \
        P8 = (oky2 && okxp) ? src_[offp + WW] : 0u;                              \
        const uint4* wsrc_ = (const uint4*)(wfrag + (size_t)(KS) * 8192);        \
        W0 = wsrc_[tid];       W1 = wsrc_[256 + tid];                            \
        W2 = wsrc_[512 + tid]; W3 = wsrc_[768 + tid];                            \
    } while (0)

#define CONV_UNPACK(BUF, P0,P1,P2,P3,P4,P5,P6,P7,P8, W0,W1,W2,W3)                \
    do {                                                                         \
        unsigned short h16[16], l16[16];                                         \
        h16[0] = (unsigned short)(P0 & 0xffffu);  l16[0] = (unsigned short)(P0 >> 16); \
        h16[1] = (unsigned short)(P1 & 0xffffu);  l16[1] = (unsigned short)(P1 >> 16); \
        h16[2] = (unsigned short)(P2 & 0xffffu);  l16[2] = (unsigned short)(P2 >> 16); \
        h16[3] = (unsigned short)(P3 & 0xffffu);  l16[3] = (unsigned short)(P3 >> 16); \
        h16[4] = (unsigned short)(P4 & 0xffffu);  l16[4] = (unsigned short)(P4 >> 16); \
        h16[5] = (unsigned short)(P5 & 0xffffu);  l16[5] = (unsigned short)(P5 >> 16); \
        h16[6] = (unsigned short)(P6 & 0xffffu);  l16[6] = (unsigned short)(P6 >> 16); \
        h16[7] = (unsigned short)(P7 & 0xffffu);  l16[7] = (unsigned short)(P7 >> 16); \
        h16[8] = (unsigned short)(P8 & 0xffffu);  l16[8] = (unsigned short)(P8 >> 16); \
        _Pragma("unroll")                                                        \
        for (int j = 9; j < 16; ++j) { h16[j] = 0; l16[j] = 0; }                 \
        *(u16x8*)&plds[BUF][(0 * 64 + spix) * 64 + xs0] = *(u16x8*)&h16[0];      \
        *(u16x8*)&plds[BUF][(0 * 64 + spix) * 64 + xs1] = *(u16x8*)&h16[8];      \
        *(u16x8*)&plds[BUF][(1 * 64 + spix) * 64 + xs0] = *(u16x8*)&l16[0];      \
        *(u16x8*)&plds[BUF][(1 * 64 + spix) * 64 + xs1] = *(u16x8*)&l16[8];      \
        uint4* wdst_ = (uint4*)&wlds[BUF][0];                                    \
        wdst_[tid]       = W0;  wdst_[256 + tid] = W1;                           \
        wdst_[512 + tid] = W2;  wdst_[768 + tid] = W3;                           \
    } while (0)

#define CONV_MFMA(BUF)                                                           \
    do {                                                                         \
        _Pragma("unroll")                                                        \
        for (int ksub = 0; ksub < 2; ++ksub) {                                   \
            const int xs = (((ksub * 4 + g) ^ (rl & 7)) << 3);                   \
            const int row = wv * 16 + rl;                                        \
            const f16x8 bh = *(const f16x8*)&plds[BUF][(0 * 64 + row) * 64 + xs];  \
            const f16x8 bl = *(const f16x8*)&plds[BUF][(1 * 64 + row) * 64 + xs];  \
            _Pragma("unroll")                                                    \
            for (int ct = 0; ct < 4; ++ct) {                                     \
                const int rowa = ct * 16 + rl;                                   \
                const f16x8 ah = *(const f16x8*)&wlds[BUF][(0 * 64 + rowa) * 64 + xs]; \
                const f16x8 al = *(const f16x8*)&wlds[BUF][(1 * 64 + rowa) * 64 + xs]; \
                acc[ct] = __builtin_amdgcn_mfma_f32_16x16x32_f16(ah, bh, acc[ct], 0, 0, 0); \
                acc[ct] = __builtin_amdgcn_mfma_f32_16x16x32_f16(ah, bl, acc[ct], 0, 0, 0); \
                acc[ct] = __builtin_amdgcn_mfma_f32_16x16x32_f16(al, bh, acc[ct], 0, 0, 0); \
            }                                                                    \
        }                                                                        \
    } while (0)

__global__ __launch_bounds__(256) void conv_kernel(const unsigned int* __restrict__ aohl,
                                                   const unsigned short* __restrict__ wfrag,
                                                   const float* __restrict__ bias,
                                                   float* __restrict__ out) {
    const int bid = blockIdx.x;
    const int swz = (bid & 7) * 128 + (bid >> 3);   // XCD-chunked
    const int b = swz >> 8;
    const int rem = swz & 255;
    const int y = rem >> 1;
    const int colbase = (rem & 1) * 64;
    const int tid = threadIdx.x;
    const int lane = tid & 63;
    const int wv = tid >> 6;
    const int rl = lane & 15;
    const int g  = lane >> 4;

    __shared__ unsigned short plds[2][2 * 64 * 64];   // 2 x 16384 B
    __shared__ unsigned short wlds[2][2 * 64 * 64];   // 2 x 16384 B

    f32x4 acc[4];
#pragma unroll
    for (int ct = 0; ct < 4; ++ct) acc[ct] = (f32x4)0.f;

    const unsigned int* aob = aohl + (size_t)b * 64 * LL;
    const int spix = tid & 63;       // staging pixel (local)
    const int scis = tid >> 6;       // staging ci-select 0..3

    // fixed staging geometry
    const int xc   = colbase + spix;
    const int off0 = y * WW + xc;
    const int offm = off0 - 1;
    const int offp = off0 + 1;
    const bool oky0 = (y > 0);
    const bool oky2 = (y < HH - 1);
    const bool okxm = (xc > 0);
    const bool okxp = (xc < WW - 1);
    const int xs0 = (((2 * scis)     ^ (spix & 7)) << 3);
    const int xs1 = (((2 * scis + 1) ^ (spix & 7)) << 3);

    unsigned int a0, a1, a2, a3, a4, a5, a6, a7, a8;
    unsigned int b0, b1, b2, b3, b4, b5, b6, b7, b8;
    uint4 wa0, wa1, wa2, wa3;
    uint4 wb0, wb1, wb2, wb3;

    CONV_PF(0, a0,a1,a2,a3,a4,a5,a6,a7,a8, wa0,wa1,wa2,wa3);
    CONV_PF(1, b0,b1,b2,b3,b4,b5,b6,b7,b8, wb0,wb1,wb2,wb3);

    for (int ks2 = 0; ks2 < 16; ks2 += 2) {
        // ---- even kstep: set A -> buffer 0 ----
        CONV_UNPACK(0, a0,a1,a2,a3,a4,a5,a6,a7,a8, wa0,wa1,wa2,wa3);
        __syncthreads();
        if (ks2 + 2 < 16) CONV_PF(ks2 + 2, a0,a1,a2,a3,a4,a5,a6,a7,a8, wa0,wa1,wa2,wa3);
        CONV_MFMA(0);

        // ---- odd kstep: set B -> buffer 1 ----
        CONV_UNPACK(1, b0,b1,b2,b3,b4,b5,b6,b7,b8, wb0,wb1,wb2,wb3);
        __syncthreads();
        if (ks2 + 3 < 16) CONV_PF(ks2 + 3, b0,b1,b2,b3,b4,b5,b6,b7,b8, wb0,wb1,wb2,wb3);
        CONV_MFMA(1);
    }

#pragma unroll
    for (int ct = 0; ct < 4; ++ct) {
        const int co_b = ct * 16 + g * 4;
        const int px = colbase + wv * 16 + rl;
#pragma unroll
        for (int j = 0; j < 4; ++j) {
            const int co = co_b + j;
            out[((size_t)b * 64 + co) * LL + y * WW + px] = acc[ct][j] + bias[co];
        }
    }
}

extern "C" void kernel_launch(void* const* d_in, const int* in_sizes, int n_in,
                              void* d_out, int out_size, void* d_ws, size_t ws_size,
                              hipStream_t stream) {
    const float* x      = (const float*)d_in[0];
    const float* qkv_w  = (const float*)d_in[1];
    const float* qkv_b  = (const float*)d_in[2];
    const float* proj_w = (const float*)d_in[3];
    const float* proj_b = (const float*)d_in[4];
    float* out = (float*)d_out;
    float* ws  = (float*)d_ws;

    const size_t n1 = (size_t)4 * 64 * LL;      // one B*C*L plane set
    float* qb   = ws;
    float* kb   = ws + n1;
    float* vb   = ws + 2 * n1;
    unsigned int* aohl = (unsigned int*)(ws + 3 * n1);
    float* KV   = ws + 4 * n1;                  // 4*8*8*9*8 = 18432 floats
    float* KS   = KV + 4 * 8 * 8 * 9 * 8;       // 4*8*8*9  = 2304 floats
    float* KVp  = KS + 4 * 8 * 8 * 9;           // 32*32*648 = 663552 floats
    unsigned short* wfrag = (unsigned short*)(KVp + (size_t)32 * KVCHUNKS * 648);  // 131072 halfs

    wprep_kernel<<<256, 256, 0, stream>>>(proj_w, wfrag);
    qkv_kernel<<<dim3(128, 4, 3), 256, 0, stream>>>(x, qkv_w, qkv_b, qb, kb, vb);
    kv_kernel<<<dim3(KVCHUNKS, NH, 4), 256, 0, stream>>>(kb, vb, KVp);
    kv_finalize<<<32, 256, 0, stream>>>(KVp, KV, KS);
    attn_kernel<<<dim3(128, NH, 4), 128, 0, stream>>>(qb, KV, KS, aohl);
    conv_kernel<<<1024, 256, 0, stream>>>(aohl, wfrag, proj_b, out);
}

// Round 17
// 106.468 us; speedup vs baseline: 1.2495x; 1.0916x over previous
//
#include <hip/hip_runtime.h>
#include <hip/hip_fp16.h>

#define LL 16384
#define HH 128
#define WW 128
#define CC 64
#define NH 8
#define EPSF 1e-7f
#define KVCHUNKS 32

typedef __attribute__((ext_vector_type(8))) _Float16 f16x8;
typedef __attribute__((ext_vector_type(4))) float f32x4;
typedef __attribute__((ext_vector_type(8))) unsigned short u16x8;

// ---------------- Kernel A: qkv 1x1 conv + bias (+relu on q,k) via MFMA hi/lo ----------
__global__ void qkv_kernel(const float* __restrict__ x, const float* __restrict__ w,
                           const float* __restrict__ bias,
                           float* __restrict__ q, float* __restrict__ k, float* __restrict__ v) {
    const int pix0 = blockIdx.x * 128;
    const int b    = blockIdx.y;
    const int sec  = blockIdx.z;
    const int tid  = threadIdx.x;
    const int lane = tid & 63;
    const int wv   = tid >> 6;

    __shared__ _Float16 xh[128][72], xl[128][72];
    __shared__ _Float16 wh[64][72],  wl[64][72];

    {
        const float* xb = x + (size_t)b * CC * LL + pix0;
        for (int idx = tid; idx < 64 * 128; idx += 256) {
            const int ci = idx >> 7;
            const int px = idx & 127;
            const float vv = xb[(size_t)ci * LL + px];
            const _Float16 h = (_Float16)vv;
            xh[px][ci] = h;
            xl[px][ci] = (_Float16)(vv - (float)h);
        }
    }
    {
        const float* wsec = w + (size_t)sec * 64 * 64;
        for (int idx = tid; idx < 64 * 64; idx += 256) {
            const int co = idx >> 6;
            const int ci = idx & 63;
            const float vv = wsec[co * 64 + ci];
            const _Float16 h = (_Float16)vv;
            wh[co][ci] = h;
            wl[co][ci] = (_Float16)(vv - (float)h);
        }
    }
    __syncthreads();

    f32x4 acc[4][2];
#pragma unroll
    for (int ct = 0; ct < 4; ++ct)
#pragma unroll
        for (int pt = 0; pt < 2; ++pt) acc[ct][pt] = (f32x4)0.f;

    const int g8 = (lane >> 4) * 8;
    const int rl = lane & 15;

#pragma unroll
    for (int ks = 0; ks < 2; ++ks) {
        const int kb = ks * 32 + g8;
        f16x8 ah[4], al[4], bh[2], bl[2];
#pragma unroll
        for (int ct = 0; ct < 4; ++ct) {
            ah[ct] = *(const f16x8*)&wh[ct * 16 + rl][kb];
            al[ct] = *(const f16x8*)&wl[ct * 16 + rl][kb];
        }
#pragma unroll
        for (int pt = 0; pt < 2; ++pt) {
            bh[pt] = *(const f16x8*)&xh[wv * 32 + pt * 16 + rl][kb];
            bl[pt] = *(const f16x8*)&xl[wv * 32 + pt * 16 + rl][kb];
        }
#pragma unroll
        for (int ct = 0; ct < 4; ++ct)
#pragma unroll
            for (int pt = 0; pt < 2; ++pt) {
                acc[ct][pt] = __builtin_amdgcn_mfma_f32_16x16x32_f16(ah[ct], bh[pt], acc[ct][pt], 0, 0, 0);
                acc[ct][pt] = __builtin_amdgcn_mfma_f32_16x16x32_f16(ah[ct], bl[pt], acc[ct][pt], 0, 0, 0);
                acc[ct][pt] = __builtin_amdgcn_mfma_f32_16x16x32_f16(al[ct], bh[pt], acc[ct][pt], 0, 0, 0);
            }
    }

    float* dst = (sec == 0) ? q : (sec == 1) ? k : v;
    const bool do_relu = (sec < 2);
#pragma unroll
    for (int ct = 0; ct < 4; ++ct) {
        const int co_b = ct * 16 + (lane >> 4) * 4;
#pragma unroll
        for (int pt = 0; pt < 2; ++pt) {
            const int px = pix0 + wv * 32 + pt * 16 + rl;
#pragma unroll
            for (int j = 0; j < 4; ++j) {
                const int co = co_b + j;
                float val = acc[ct][pt][j] + bias[sec * 64 + co];
                if (do_relu) val = fmaxf(val, 0.f);
                dst[((size_t)b * 64 + co) * LL + px] = val;
            }
        }
    }
}

// ---------------- Kernel B: KV/KS partials, K staged in LDS ----------------
__global__ void kv_kernel(const float* __restrict__ k, const float* __restrict__ v,
                          float* __restrict__ KVp) {
    const int chunk = blockIdx.x;
    const int h = blockIdx.y;
    const int b = blockIdx.z;
    const int tid = threadIdx.x;
    const int c  = tid >> 5;
    const int s  = tid & 31;
    const int half = s >> 4;
    const int sl   = s & 15;
    const int cpb  = half * 4;

    __shared__ float klds[8][6][130];

    {
        const float* kb = k + ((size_t)(b * 64) + 8 * h) * LL;
        for (int t = tid; t < 8 * 6 * 130; t += 256) {
            const int ch = t / 780;
            const int r1 = t - ch * 780;
            const int lr = r1 / 130;
            const int cx = r1 - lr * 130;
            const int gy = chunk * 4 + lr - 1;
            const int gx = cx - 1;
            const bool ok = (gy >= 0 && gy < HH && gx >= 0 && gx < WW);
            klds[ch][lr][cx] = ok ? kb[(size_t)ch * LL + gy * WW + gx] : 0.f;
        }
    }
    __syncthreads();

    const float* vb = v + ((size_t)(b * 64) + 8 * h + cpb) * LL;

    float kv4[9][4] = {{0.f}};
    float ks[9] = {0.f};

    for (int r = 0; r < 4; ++r) {
        const int y = chunk * 4 + r;
        for (int g = 0; g < 8; ++g) {
            const int col = g * 16 + sl;
            float vv[4];
#pragma unroll
            for (int cp = 0; cp < 4; ++cp) vv[cp] = vb[(size_t)cp * LL + y * WW + col];
            float k9[9];
#pragma unroll
            for (int dy = 0; dy < 3; ++dy)
#pragma unroll
                for (int dx = 0; dx < 3; ++dx)
                    k9[dy * 3 + dx] = klds[c][r + dy][col + dx];
#pragma unroll
            for (int p = 0; p < 9; ++p) {
                ks[p] += k9[p];
#pragma unroll
                for (int cp = 0; cp < 4; ++cp)
                    kv4[p][cp] = fmaf(k9[p], vv[cp], kv4[p][cp]);
            }
        }
    }

#pragma unroll
    for (int p = 0; p < 9; ++p) {
#pragma unroll
        for (int m = 8; m >= 1; m >>= 1) ks[p] += __shfl_xor(ks[p], m);
#pragma unroll
        for (int cp = 0; cp < 4; ++cp) {
#pragma unroll
            for (int m = 8; m >= 1; m >>= 1) kv4[p][cp] += __shfl_xor(kv4[p][cp], m);
        }
    }

    if (sl == 0) {
        float* dst = KVp + (((size_t)(b * NH + h) * KVCHUNKS) + chunk) * 648;
#pragma unroll
        for (int p = 0; p < 9; ++p) {
#pragma unroll
            for (int cp = 0; cp < 4; ++cp)
                dst[(c * 9 + p) * 8 + cpb + cp] = kv4[p][cp];
            if (half == 0) dst[576 + c * 9 + p] = ks[p];
        }
    }
}

// ---------------- Kernel B2: reduce 32 chunk-partials -> KV, KS ----------------
__global__ void kv_finalize(const float* __restrict__ KVp,
                            float* __restrict__ KV, float* __restrict__ KS) {
    const int bh = blockIdx.x;
    const float* src = KVp + (size_t)bh * KVCHUNKS * 648;
    for (int idx = threadIdx.x; idx < 648; idx += 256) {
        float s0 = 0.f, s1 = 0.f, s2 = 0.f, s3 = 0.f;
#pragma unroll
        for (int ch = 0; ch < KVCHUNKS; ch += 4) {
            s0 += src[(ch + 0) * 648 + idx];
            s1 += src[(ch + 1) * 648 + idx];
            s2 += src[(ch + 2) * 648 + idx];
            s3 += src[(ch + 3) * 648 + idx];
        }
        const float sum = (s0 + s1) + (s2 + s3);
        if (idx < 576) KV[(size_t)bh * 576 + idx] = sum;
        else           KS[(size_t)bh * 72 + (idx - 576)] = sum;
    }
}

// ---------------- Kernel C: attn (global-load version), writes packed f16 hi/lo ------
__global__ void attn_kernel(const float* __restrict__ q, const float* __restrict__ KV,
                            const float* __restrict__ KS, unsigned int* __restrict__ aohl) {
    const int y = blockIdx.x;
    const int h = blockIdx.y;
    const int b = blockIdx.z;
    const int col = threadIdx.x;

    float out[8] = {0.f};
    float den = 0.f;
    const int kvbase = (b * NH + h) * 8;

    for (int c = 0; c < 8; ++c) {
        const float* qc = q + ((size_t)(b * 64) + 8 * h + c) * LL;
        float q9[9];
#pragma unroll
        for (int dy = -1; dy <= 1; ++dy)
#pragma unroll
            for (int dx = -1; dx <= 1; ++dx) {
                const int yy = y + dy, xx = col + dx;
                const bool ok = (yy >= 0 && yy < HH && xx >= 0 && xx < WW);
                q9[(dy + 1) * 3 + (dx + 1)] = ok ? qc[yy * WW + xx] : 0.f;
            }
        const float* kvr = KV + ((size_t)(kvbase + c) * 9) * 8;
        const float* ksr = KS + (size_t)(kvbase + c) * 9;
#pragma unroll
        for (int p = 0; p < 9; ++p) {
            const float qv = q9[p];
            den += qv * ksr[p];
#pragma unroll
            for (int cp = 0; cp < 8; ++cp) out[cp] += qv * kvr[p * 8 + cp];
        }
    }
    const float inv = 1.f / (den + EPSF);
    const int pix = y * WW + col;
#pragma unroll
    for (int cp = 0; cp < 8; ++cp) {
        const float val = out[cp] * inv;
        const _Float16 hf = (_Float16)val;
        const _Float16 lf = (_Float16)(val - (float)hf);
        unsigned short hb, lb;
        __builtin_memcpy(&hb, &hf, 2);
        __builtin_memcpy(&lb, &lf, 2);
        aohl[((size_t)(b * 64) + h * 8 + cp) * LL + pix] = (unsigned int)hb | ((unsigned int)lb << 16);
    }
}

// ---------------- Kernel W: pre-split proj_w into MFMA fragment layout (single f16) --
// wfrag[ks(16)][co(64)][k(64)] halfs; 16B slot index XOR'd with (co&7).
__global__ void wprep_kernel(const float* __restrict__ w, unsigned short* __restrict__ wfrag) {
    const int idx = blockIdx.x * 256 + threadIdx.x;   // 16*64*64 = 65536
    const int k  = idx & 63;
    const int co = (idx >> 6) & 63;
    const int ks = idx >> 12;
    const int kg = ks * 64 + k;
    const int ci = kg >> 4, tap = kg & 15;
    const float vv = (tap < 9) ? w[(co * 64 + ci) * 9 + tap] : 0.f;
    const _Float16 h = (_Float16)vv;   // single-f16 W (error analysed: ~5e-4 worst-case)
    unsigned short hb;
    __builtin_memcpy(&hb, &h, 2);
    const int kx = (((k >> 3) ^ (co & 7)) << 3) | (k & 7);
    wfrag[((size_t)ks * 64 + co) * 64 + kx] = hb;
}

// ---------------- Kernel D: 3x3 conv via MFMA; W single-f16, P hi/lo; dbuf LDS ------
// grid 1024 (XCD-chunk swizzled): block -> (b, row y, col-half), 64 pix.
// 16 ksteps of K=64 (4 ci). Depth-1 named-reg prefetch.
// W buffer = 4096 halfs = 512 uint4 -> 2 uint4 PER THREAD (R16 bug: only 1 was
// staged, leaving half of wlds uninitialized -> NaN).
#define CONV_PREFETCH(KS)                                                        \
    do {                                                                         \
        const unsigned int* src_ = aob + (size_t)((KS) * 4 + scis) * LL;         \
        pf0 = (oky0 && okxm) ? src_[offm - WW] : 0u;                             \
        pf1 = oky0 ? src_[off0 - WW] : 0u;                                       \
        pf2 = (oky0 && okxp) ? src_[offp - WW] : 0u;                             \
        pf3 = okxm ? src_[offm] : 0u;                                            \
        pf4 = src_[off0];                                                        \
        pf5 = okxp ? src_[offp] : 0u;                                            \
        pf6 = (oky2 && okxm) ? src_[offm + WW] : 0u;                             \
        pf7 = oky2 ? src_[off0 + WW] : 0u;                                       \
        pf8 = (oky2 && okxp) ? src_[offp + WW] : 0u;                             \
        const uint4* wsrc_ = (const uint4*)(wfrag + (size_t)(KS) * 4096);        \
        wf0 = wsrc_[tid];                                                        \
        wf1 = wsrc_[256 + tid];                                                  \
    } while (0)

__global__ __launch_bounds__(256) void conv_kernel(const unsigned int* __restrict__ aohl,
                                                   const unsigned short* __restrict__ wfrag,
                                                   const float* __restrict__ bias,
                                                   float* __restrict__ out) {
    const int bid = blockIdx.x;
    const int swz = (bid & 7) * 128 + (bid >> 3);   // XCD-chunked
    const int b = swz >> 8;
    const int rem = swz & 255;
    const int y = rem >> 1;
    const int colbase = (rem & 1) * 64;
    const int tid = threadIdx.x;
    const int lane = tid & 63;
    const int wv = tid >> 6;
    const int rl = lane & 15;
    const int g  = lane >> 4;

    __shared__ unsigned short plds[2][2 * 64 * 64];   // 2 x 16384 B (P hi/lo)
    __shared__ unsigned short wlds[2][64 * 64];       // 2 x  8192 B (W single)

    f32x4 acc[4];
#pragma unroll
    for (int ct = 0; ct < 4; ++ct) acc[ct] = (f32x4)0.f;

    const unsigned int* aob = aohl + (size_t)b * 64 * LL;
    const int spix = tid & 63;       // staging pixel (local)
    const int scis = tid >> 6;       // staging ci-select 0..3

    // fixed staging geometry
    const int xc   = colbase + spix;
    const int off0 = y * WW + xc;
    const int offm = off0 - 1;
    const int offp = off0 + 1;
    const bool oky0 = (y > 0);
    const bool oky2 = (y < HH - 1);
    const bool okxm = (xc > 0);
    const bool okxp = (xc < WW - 1);
    const int xs0 = (((2 * scis)     ^ (spix & 7)) << 3);
    const int xs1 = (((2 * scis + 1) ^ (spix & 7)) << 3);

    unsigned int pf0, pf1, pf2, pf3, pf4, pf5, pf6, pf7, pf8;
    uint4 wf0, wf1;

    CONV_PREFETCH(0);

    for (int ks = 0; ks < 16; ++ks) {
        const int cur = ks & 1;
        // ---- unpack named regs -> LDS[cur] ----
        {
            unsigned short h16[16], l16[16];
            h16[0] = (unsigned short)(pf0 & 0xffffu);  l16[0] = (unsigned short)(pf0 >> 16);
            h16[1] = (unsigned short)(pf1 & 0xffffu);  l16[1] = (unsigned short)(pf1 >> 16);
            h16[2] = (unsigned short)(pf2 & 0xffffu);  l16[2] = (unsigned short)(pf2 >> 16);
            h16[3] = (unsigned short)(pf3 & 0xffffu);  l16[3] = (unsigned short)(pf3 >> 16);
            h16[4] = (unsigned short)(pf4 & 0xffffu);  l16[4] = (unsigned short)(pf4 >> 16);
            h16[5] = (unsigned short)(pf5 & 0xffffu);  l16[5] = (unsigned short)(pf5 >> 16);
            h16[6] = (unsigned short)(pf6 & 0xffffu);  l16[6] = (unsigned short)(pf6 >> 16);
            h16[7] = (unsigned short)(pf7 & 0xffffu);  l16[7] = (unsigned short)(pf7 >> 16);
            h16[8] = (unsigned short)(pf8 & 0xffffu);  l16[8] = (unsigned short)(pf8 >> 16);
#pragma unroll
            for (int j = 9; j < 16; ++j) { h16[j] = 0; l16[j] = 0; }
            *(u16x8*)&plds[cur][(0 * 64 + spix) * 64 + xs0] = *(u16x8*)&h16[0];
            *(u16x8*)&plds[cur][(0 * 64 + spix) * 64 + xs1] = *(u16x8*)&h16[8];
            *(u16x8*)&plds[cur][(1 * 64 + spix) * 64 + xs0] = *(u16x8*)&l16[0];
            *(u16x8*)&plds[cur][(1 * 64 + spix) * 64 + xs1] = *(u16x8*)&l16[8];
            uint4* wdst = (uint4*)&wlds[cur][0];
            wdst[tid]       = wf0;
            wdst[256 + tid] = wf1;
        }
        __syncthreads();
        if (ks < 15) CONV_PREFETCH(ks + 1);   // flies under the MFMA phase

        // ---- MFMA: 2 ksubs x 4 co-tiles x 2 (P hi/lo); W single ----
#pragma unroll
        for (int ksub = 0; ksub < 2; ++ksub) {
            const int xs = (((ksub * 4 + g) ^ (rl & 7)) << 3);
            const int row = wv * 16 + rl;
            const f16x8 bh = *(const f16x8*)&plds[cur][(0 * 64 + row) * 64 + xs];
            const f16x8 bl = *(const f16x8*)&plds[cur][(1 * 64 + row) * 64 + xs];
#pragma unroll
            for (int ct = 0; ct < 4; ++ct) {
                const int rowa = ct * 16 + rl;
                const f16x8 ah = *(const f16x8*)&wlds[cur][rowa * 64 + xs];
                acc[ct] = __builtin_amdgcn_mfma_f32_16x16x32_f16(ah, bh, acc[ct], 0, 0, 0);
                acc[ct] = __builtin_amdgcn_mfma_f32_16x16x32_f16(ah, bl, acc[ct], 0, 0, 0);
            }
        }
    }

#pragma unroll
    for (int ct = 0; ct < 4; ++ct) {
        const int co_b = ct * 16 + g * 4;
        const int px = colbase + wv * 16 + rl;
#pragma unroll
        for (int j = 0; j < 4; ++j) {
            const int co = co_b + j;
            out[((size_t)b * 64 + co) * LL + y * WW + px] = acc[ct][j] + bias[co];
        }
    }
}

extern "C" void kernel_launch(void* const* d_in, const int* in_sizes, int n_in,
                              void* d_out, int out_size, void* d_ws, size_t ws_size,
                              hipStream_t stream) {
    const float* x      = (const float*)d_in[0];
    const float* qkv_w  = (const float*)d_in[1];
    const float* qkv_b  = (const float*)d_in[2];
    const float* proj_w = (const float*)d_in[3];
    const float* proj_b = (const float*)d_in[4];
    float* out = (float*)d_out;
    float* ws  = (float*)d_ws;

    const size_t n1 = (size_t)4 * 64 * LL;      // one B*C*L plane set
    float* qb   = ws;
    float* kb   = ws + n1;
    float* vb   = ws + 2 * n1;
    unsigned int* aohl = (unsigned int*)(ws + 3 * n1);
    float* KV   = ws + 4 * n1;                  // 4*8*8*9*8 = 18432 floats
    float* KS   = KV + 4 * 8 * 8 * 9 * 8;       // 4*8*8*9  = 2304 floats
    float* KVp  = KS + 4 * 8 * 8 * 9;           // 32*32*648 = 663552 floats
    unsigned short* wfrag = (unsigned short*)(KVp + (size_t)32 * KVCHUNKS * 648);  // 65536 halfs

    wprep_kernel<<<256, 256, 0, stream>>>(proj_w, wfrag);
    qkv_kernel<<<dim3(128, 4, 3), 256, 0, stream>>>(x, qkv_w, qkv_b, qb, kb, vb);
    kv_kernel<<<dim3(KVCHUNKS, NH, 4), 256, 0, stream>>>(kb, vb, KVp);
    kv_finalize<<<32, 256, 0, stream>>>(KVp, KV, KS);
    attn_kernel<<<dim3(128, NH, 4), 128, 0, stream>>>(qb, KV, KS, aohl);
    conv_kernel<<<1024, 256, 0, stream>>>(aohl, wfrag, proj_b, out);
}